// Round 12
// baseline (82.651 us; speedup 1.0000x reference)
//
#include <hip/hip_runtime.h>
#include <stdint.h>

// ---------------------------------------------------------------------------
// GraphSAGE SampleAndAggregate — RNG VERIFIED (round 5, variant 5):
//   modern JAX: partitionable threefry, foldlike split, and randint's
//   INTERNAL k1,k2=split(key); col_i = (x0^x1)(tf(tf(key,(0,1)),(0,i))) & 127
// DO NOT change the RNG path.
// ---------------------------------------------------------------------------
#define N_NODES 100000
#define F_DIM   256
#define H_DIM   128
#define MAX_DEG 128
#define BATCH   512
#define S1N     25
#define S2N     10
#define NS1     (BATCH * S2N)   // 5120
#define NS2     (NS1 * S1N)     // 128000

__device__ __forceinline__ void tf2(uint32_t k0, uint32_t k1, uint32_t c0, uint32_t c1,
                                    uint32_t& o0, uint32_t& o1) {
  uint32_t ks0 = k0, ks1 = k1, ks2 = k0 ^ k1 ^ 0x1BD11BDAu;
  uint32_t x0 = c0 + ks0;
  uint32_t x1 = c1 + ks1;
#define TF_ROUND(r) { x0 += x1; x1 = (x1 << (r)) | (x1 >> (32 - (r))); x1 ^= x0; }
  TF_ROUND(13); TF_ROUND(15); TF_ROUND(26); TF_ROUND(6);
  x0 += ks1; x1 += ks2 + 1u;
  TF_ROUND(17); TF_ROUND(29); TF_ROUND(16); TF_ROUND(24);
  x0 += ks2; x1 += ks0 + 2u;
  TF_ROUND(13); TF_ROUND(15); TF_ROUND(26); TF_ROUND(6);
  x0 += ks0; x1 += ks1 + 3u;
  TF_ROUND(17); TF_ROUND(29); TF_ROUND(16); TF_ROUND(24);
  x0 += ks1; x1 += ks2 + 4u;
  TF_ROUND(13); TF_ROUND(15); TF_ROUND(26); TF_ROUND(6);
  x0 += ks2; x1 += ks0 + 5u;
#undef TF_ROUND
  o0 = x0; o1 = x1;
}

// col draw i of randint(subkey_idx, ..., 0, 128) under verified semantics
__device__ __forceinline__ uint32_t jax_col(int subkey_idx, uint32_t i) {
  uint32_t k0, k1, kk0, kk1, o0, o1;
  tf2(0u, 42u, 0u, (uint32_t)subkey_idx, k0, k1);  // foldlike split of key(42)
  tf2(k0, k1, 0u, 1u, kk0, kk1);                   // randint internal k2
  tf2(kk0, kk1, 0u, i, o0, o1);                    // lower_bits draw i
  return (o0 ^ o1) & (MAX_DEG - 1);
}

// async global(16B/lane) -> LDS (wave-uniform base + lane*16), zero VGPR dest
__device__ __forceinline__ void gload_lds16(const float* g, float* l) {
  __builtin_amdgcn_global_load_lds(
      (const __attribute__((address_space(1))) void*)g,
      (__attribute__((address_space(3))) void*)l, 16, 0, 0);
}

// ---------------------------------------------------------------------------
// K1 (fused sample + gather + layer-0 matmul for the 5120 h1 rows).
// Grid 1280, block 256 (4 waves). Wave w owns s1-row r0+w.
// Gather via global_load_lds: 13 row-loads in flight per wave (no VGPR
// destinations -> regalloc cannot serialize them; r9-r11 all collapsed to
// VGPR<=36 / ~4 loads in flight). Two 13-row batches through a 13-KB/wave
// LDS stage; sums are contiguous ds_read_b128 (conflict-free).
#define RMM 4
__global__ __launch_bounds__(256) void k_gmm(const float* __restrict__ feat,
                                             const int* __restrict__ adj,
                                             const int* __restrict__ batch,
                                             const float* __restrict__ Ws,
                                             const float* __restrict__ Wn,
                                             float* __restrict__ Xself,
                                             float* __restrict__ h1out) {
  __shared__ int   nbr[RMM][26];          // [.][25] = self (s1)
  __shared__ float stage[RMM][13][256];   // 52 KB staging
  __shared__ float xl[512][4];            // 8 KB transposed X tile
  const int tid = threadIdx.x;
  const int r0 = blockIdx.x * RMM;

  if (tid < RMM * 26) {
    int rr = tid / 26, t = tid % 26;
    int r = r0 + rr;
    uint32_t c0 = jax_col(0, (uint32_t)r);
    int s1 = adj[(size_t)batch[r / S2N] * MAX_DEG + c0];
    if (t < 25) {
      uint32_t col = jax_col(1, (uint32_t)(r * S1N + t));
      nbr[rr][t] = adj[(size_t)s1 * MAX_DEG + col];
    } else {
      nbr[rr][25] = s1;
    }
  }
  __syncthreads();

  // ---- gather: wave w -> row w; 13 async loads in flight per batch ----
  {
    const int w = tid >> 6, lane = tid & 63;
    const int k0 = lane * 4;

    // batch A: neighbor rows 0..12
#pragma unroll
    for (int t = 0; t < 13; ++t)
      gload_lds16(&feat[(size_t)nbr[w][t] * F_DIM + k0], &stage[w][t][0]);
    asm volatile("s_waitcnt vmcnt(0)" ::: "memory");
    __builtin_amdgcn_sched_barrier(0);

    float4 p[4];
#pragma unroll
    for (int i = 0; i < 4; ++i) p[i] = make_float4(0.f, 0.f, 0.f, 0.f);
#pragma unroll
    for (int t = 0; t < 13; ++t) {
      const float4 v = *reinterpret_cast<const float4*>(&stage[w][t][k0]);
      p[t & 3].x += v.x; p[t & 3].y += v.y; p[t & 3].z += v.z; p[t & 3].w += v.w;
    }
    asm volatile("s_waitcnt lgkmcnt(0)" ::: "memory");  // A reads done before B overwrites
    __builtin_amdgcn_sched_barrier(0);

    // batch B: neighbor rows 13..24 into slots 0..11, self into slot 12
#pragma unroll
    for (int t = 13; t < 26; ++t)
      gload_lds16(&feat[(size_t)nbr[w][t] * F_DIM + k0], &stage[w][t - 13][0]);
    asm volatile("s_waitcnt vmcnt(0)" ::: "memory");
    __builtin_amdgcn_sched_barrier(0);

#pragma unroll
    for (int t = 0; t < 12; ++t) {
      const float4 v = *reinterpret_cast<const float4*>(&stage[w][t][k0]);
      p[t & 3].x += v.x; p[t & 3].y += v.y; p[t & 3].z += v.z; p[t & 3].w += v.w;
    }
    const float4 s = *reinterpret_cast<const float4*>(&stage[w][12][k0]);

    float4 a;
    a.x = (p[0].x + p[1].x) + (p[2].x + p[3].x);
    a.y = (p[0].y + p[1].y) + (p[2].y + p[3].y);
    a.z = (p[0].z + p[1].z) + (p[2].z + p[3].z);
    a.w = (p[0].w + p[1].w) + (p[2].w + p[3].w);

    // self half to global for k_tail's h0-neighbor-mean
    *reinterpret_cast<float4*>(&Xself[(size_t)(r0 + w) * 256 + k0]) = s;

    // transposed LDS store (one-time; write conflicts tolerated)
    const float inv = 1.f / (float)S1N;
    xl[k0 + 0][w] = s.x;  xl[k0 + 1][w] = s.y;
    xl[k0 + 2][w] = s.z;  xl[k0 + 3][w] = s.w;
    xl[256 + k0 + 0][w] = a.x * inv; xl[256 + k0 + 1][w] = a.y * inv;
    xl[256 + k0 + 2][w] = a.z * inv; xl[256 + k0 + 3][w] = a.w * inv;
  }
  __syncthreads();

  // ---- mm phase (same math as verified r6/r8; 4 rows per thread) ----
  const int j = tid & (H_DIM - 1);
  const int h = tid >> 7;                          // 0: self@Ws, 1: mean@Wn
  const float* __restrict__ W = h ? Wn : Ws;
  float acc[RMM] = {0.f, 0.f, 0.f, 0.f};

#pragma unroll 4
  for (int k = 0; k < F_DIM; ++k) {
    float w = W[k * H_DIM + j];
    int kk = (h << 8) + k;
    float4 xa = *reinterpret_cast<const float4*>(&xl[kk][0]);
    acc[0] += xa.x * w; acc[1] += xa.y * w; acc[2] += xa.z * w; acc[3] += xa.w * w;
  }
#pragma unroll
  for (int i = 0; i < RMM; ++i)
    h1out[(size_t)(r0 + i) * 256 + (h << 7) + j] = fmaxf(acc[i], 0.f);
}

// ---------------------------------------------------------------------------
// K2 (fused h0 + out): per batch row b (grid 512, 256 thr). Unchanged (verified).
__global__ __launch_bounds__(256) void k_tail(const float* __restrict__ feat,
                                              const int* __restrict__ batch,
                                              const float* __restrict__ Xself,
                                              const float* __restrict__ h1out,
                                              const float* __restrict__ Ws0,
                                              const float* __restrict__ Wn0,
                                              const float* __restrict__ Ws1,
                                              const float* __restrict__ Wn1,
                                              float* __restrict__ out) {
  __shared__ float sA[2][F_DIM];
  __shared__ float sB[2][F_DIM];
  __shared__ float red[4];
  const int tid = threadIdx.x;
  const int b = blockIdx.x;
  const int j = tid & (H_DIM - 1);
  const int h = tid >> 7;

  {
    float m = 0.f;
#pragma unroll
    for (int t = 0; t < S2N; ++t)
      m += Xself[(size_t)(b * S2N + t) * 256 + tid];
    sA[1][tid] = m / (float)S2N;
    sA[0][tid] = feat[(size_t)batch[b] * F_DIM + tid];
  }
  __syncthreads();

  const float* __restrict__ W0 = h ? Wn0 : Ws0;
  float a0 = 0.f;
#pragma unroll 4
  for (int k4 = 0; k4 < F_DIM / 4; ++k4) {
    float4 s4 = *reinterpret_cast<const float4*>(&sA[h][k4 * 4]);
    a0 += s4.x * W0[(k4 * 4 + 0) * H_DIM + j];
    a0 += s4.y * W0[(k4 * 4 + 1) * H_DIM + j];
    a0 += s4.z * W0[(k4 * 4 + 2) * H_DIM + j];
    a0 += s4.w * W0[(k4 * 4 + 3) * H_DIM + j];
  }
  a0 = fmaxf(a0, 0.f);

  sB[0][tid] = a0;
  {
    float m = 0.f;
#pragma unroll
    for (int t = 0; t < S2N; ++t)
      m += h1out[(size_t)(b * S2N + t) * 256 + tid];
    sB[1][tid] = m / (float)S2N;
  }
  __syncthreads();

  const float* __restrict__ W1 = h ? Wn1 : Ws1;
  float a1 = 0.f;
#pragma unroll 4
  for (int k4 = 0; k4 < F_DIM / 4; ++k4) {
    float4 s4 = *reinterpret_cast<const float4*>(&sB[h][k4 * 4]);
    a1 += s4.x * W1[(k4 * 4 + 0) * H_DIM + j];
    a1 += s4.y * W1[(k4 * 4 + 1) * H_DIM + j];
    a1 += s4.z * W1[(k4 * 4 + 2) * H_DIM + j];
    a1 += s4.w * W1[(k4 * 4 + 3) * H_DIM + j];
  }

  float s = a1 * a1;
#pragma unroll
  for (int off = 32; off > 0; off >>= 1) s += __shfl_xor(s, off);
  if ((tid & 63) == 0) red[tid >> 6] = s;
  __syncthreads();
  float tot = red[0] + red[1] + red[2] + red[3];
  float inv = 1.f / fmaxf(sqrtf(tot), 1e-12f);
  out[(size_t)b * 256 + tid] = a1 * inv;
}

// ---------------------------------------------------------------------------
extern "C" void kernel_launch(void* const* d_in, const int* in_sizes, int n_in,
                              void* d_out, int out_size, void* d_ws, size_t ws_size,
                              hipStream_t stream) {
  const float* feat  = (const float*)d_in[0];
  const int*   adj   = (const int*)d_in[1];
  const int*   batch = (const int*)d_in[2];
  const float* Ws0   = (const float*)d_in[3];
  const float* Wn0   = (const float*)d_in[4];
  const float* Ws1   = (const float*)d_in[5];
  const float* Wn1   = (const float*)d_in[6];
  float* out = (float*)d_out;

  char* ws = (char*)d_ws;
  float* Xself = (float*)(ws);                    // 5120*256*4 = 5.25 MB
  float* h1out = (float*)(ws + (8u << 20));       // 5120*256*4 = 5.25 MB

  k_gmm <<<NS1 / RMM, 256, 0, stream>>>(feat, adj, batch, Ws0, Wn0, Xself, h1out);
  k_tail<<<BATCH, 256, 0, stream>>>(feat, batch, Xself, h1out, Ws0, Wn0, Ws1, Wn1, out);
}

// Round 13
// 54.282 us; speedup vs baseline: 1.5226x; 1.5226x over previous
//
#include <hip/hip_runtime.h>
#include <stdint.h>

// ---------------------------------------------------------------------------
// GraphSAGE SampleAndAggregate — RNG VERIFIED (round 5, variant 5):
//   modern JAX: partitionable threefry, foldlike split, and randint's
//   INTERNAL k1,k2=split(key); col_i = (x0^x1)(tf(tf(key,(0,1)),(0,i))) & 127
// DO NOT change the RNG path.
//
// Gather-bottleneck history (r9-r12): four structurally distinct gather
// implementations (register ILP, forced 26-reg ILP, LDS-DMA, 2x occupancy)
// all converge to ~1.0-1.25 TB/s — the random-1KB-row service ceiling
// (~64 lines/CU x 64B / ~900ns x 256 CU = 1.16 TB/s). This file is the
// proven-best r10 structure, reverted after the r12 LDS-DMA regression.
// ---------------------------------------------------------------------------
#define N_NODES 100000
#define F_DIM   256
#define H_DIM   128
#define MAX_DEG 128
#define BATCH   512
#define S1N     25
#define S2N     10
#define NS1     (BATCH * S2N)   // 5120
#define NS2     (NS1 * S1N)     // 128000

__device__ __forceinline__ void tf2(uint32_t k0, uint32_t k1, uint32_t c0, uint32_t c1,
                                    uint32_t& o0, uint32_t& o1) {
  uint32_t ks0 = k0, ks1 = k1, ks2 = k0 ^ k1 ^ 0x1BD11BDAu;
  uint32_t x0 = c0 + ks0;
  uint32_t x1 = c1 + ks1;
#define TF_ROUND(r) { x0 += x1; x1 = (x1 << (r)) | (x1 >> (32 - (r))); x1 ^= x0; }
  TF_ROUND(13); TF_ROUND(15); TF_ROUND(26); TF_ROUND(6);
  x0 += ks1; x1 += ks2 + 1u;
  TF_ROUND(17); TF_ROUND(29); TF_ROUND(16); TF_ROUND(24);
  x0 += ks2; x1 += ks0 + 2u;
  TF_ROUND(13); TF_ROUND(15); TF_ROUND(26); TF_ROUND(6);
  x0 += ks0; x1 += ks1 + 3u;
  TF_ROUND(17); TF_ROUND(29); TF_ROUND(16); TF_ROUND(24);
  x0 += ks1; x1 += ks2 + 4u;
  TF_ROUND(13); TF_ROUND(15); TF_ROUND(26); TF_ROUND(6);
  x0 += ks2; x1 += ks0 + 5u;
#undef TF_ROUND
  o0 = x0; o1 = x1;
}

// col draw i of randint(subkey_idx, ..., 0, 128) under verified semantics
__device__ __forceinline__ uint32_t jax_col(int subkey_idx, uint32_t i) {
  uint32_t k0, k1, kk0, kk1, o0, o1;
  tf2(0u, 42u, 0u, (uint32_t)subkey_idx, k0, k1);  // foldlike split of key(42)
  tf2(k0, k1, 0u, 1u, kk0, kk1);                   // randint internal k2
  tf2(kk0, kk1, 0u, i, o0, o1);                    // lower_bits draw i
  return (o0 ^ o1) & (MAX_DEG - 1);
}

// ---------------------------------------------------------------------------
// K1 (fused sample + gather + layer-0 matmul for the 5120 h1 rows).
// Grid 640, block 512. Wave w (of 8) owns s1-row r0+w.
#define RMM 8
__global__ __launch_bounds__(512, 1) void k_gmm(const float* __restrict__ feat,
                                                const int* __restrict__ adj,
                                                const int* __restrict__ batch,
                                                const float* __restrict__ Ws,
                                                const float* __restrict__ Wn,
                                                float* __restrict__ Xself,
                                                float* __restrict__ h1out) {
  __shared__ int   nbr[RMM][26];    // [.][25] = self (s1)
  __shared__ float xl[2][512][4];   // 16 KB, transposed X tile
  const int tid = threadIdx.x;
  const int r0 = blockIdx.x * RMM;

  if (tid < RMM * 26) {
    int rr = tid / 26, t = tid % 26;
    int r = r0 + rr;
    uint32_t c0 = jax_col(0, (uint32_t)r);
    int s1 = adj[(size_t)batch[r / S2N] * MAX_DEG + c0];
    if (t < 25) {
      uint32_t col = jax_col(1, (uint32_t)(r * S1N + t));
      nbr[rr][t] = adj[(size_t)s1 * MAX_DEG + col];
    } else {
      nbr[rr][25] = s1;
    }
  }
  __syncthreads();

  // ---- gather: wave w -> row w ----
  {
    const int w = tid >> 6, lane = tid & 63;
    const int k0 = lane * 4;

    // wave-uniform source ids -> scalar registers (saddr-form loads)
    int idx[26];
#pragma unroll
    for (int t = 0; t < 26; ++t)
      idx[t] = __builtin_amdgcn_readfirstlane(nbr[w][t]);

    float4 acc[5];
#pragma unroll
    for (int i = 0; i < 5; ++i) acc[i] = make_float4(0.f, 0.f, 0.f, 0.f);

#pragma unroll
    for (int t = 0; t < 25; ++t) {
      const float4 v =
          *reinterpret_cast<const float4*>(&feat[(size_t)idx[t] * F_DIM + k0]);
      acc[t % 5].x += v.x; acc[t % 5].y += v.y;
      acc[t % 5].z += v.z; acc[t % 5].w += v.w;
    }
    const float4 s =
        *reinterpret_cast<const float4*>(&feat[(size_t)idx[25] * F_DIM + k0]);

    float4 a;
    a.x = ((acc[0].x + acc[1].x) + (acc[2].x + acc[3].x)) + acc[4].x;
    a.y = ((acc[0].y + acc[1].y) + (acc[2].y + acc[3].y)) + acc[4].y;
    a.z = ((acc[0].z + acc[1].z) + (acc[2].z + acc[3].z)) + acc[4].z;
    a.w = ((acc[0].w + acc[1].w) + (acc[2].w + acc[3].w)) + acc[4].w;

    // self half to global for k_tail's h0-neighbor-mean
    *reinterpret_cast<float4*>(&Xself[(size_t)(r0 + w) * 256 + k0]) = s;

    // transposed LDS store (one-time; write conflicts known & tolerated)
    const int G = w >> 2, rl = w & 3;
    const float inv = 1.f / (float)S1N;
    xl[G][k0 + 0][rl] = s.x;  xl[G][k0 + 1][rl] = s.y;
    xl[G][k0 + 2][rl] = s.z;  xl[G][k0 + 3][rl] = s.w;
    xl[G][256 + k0 + 0][rl] = a.x * inv; xl[G][256 + k0 + 1][rl] = a.y * inv;
    xl[G][256 + k0 + 2][rl] = a.z * inv; xl[G][256 + k0 + 3][rl] = a.w * inv;
  }
  __syncthreads();

  // ---- mm phase (verified r6/r8 math; 4 rows per thread) ----
  const int j = tid & (H_DIM - 1);
  const int h = (tid >> 7) & 1;                    // 0: self@Ws, 1: mean@Wn
  const int q = tid >> 8;                          // row group: 0 -> 0-3, 1 -> 4-7
  const float* __restrict__ W = h ? Wn : Ws;
  float acc[4] = {0.f, 0.f, 0.f, 0.f};

#pragma unroll 4
  for (int k = 0; k < F_DIM; ++k) {
    float w = W[k * H_DIM + j];
    int kk = (h << 8) + k;
    float4 xa = *reinterpret_cast<const float4*>(&xl[q][kk][0]);
    acc[0] += xa.x * w; acc[1] += xa.y * w; acc[2] += xa.z * w; acc[3] += xa.w * w;
  }
#pragma unroll
  for (int i = 0; i < 4; ++i)
    h1out[(size_t)(r0 + q * 4 + i) * 256 + (h << 7) + j] = fmaxf(acc[i], 0.f);
}

// ---------------------------------------------------------------------------
// K2 (fused h0 + out): per batch row b (grid 512, 256 thr). Unchanged (verified).
__global__ __launch_bounds__(256) void k_tail(const float* __restrict__ feat,
                                              const int* __restrict__ batch,
                                              const float* __restrict__ Xself,
                                              const float* __restrict__ h1out,
                                              const float* __restrict__ Ws0,
                                              const float* __restrict__ Wn0,
                                              const float* __restrict__ Ws1,
                                              const float* __restrict__ Wn1,
                                              float* __restrict__ out) {
  __shared__ float sA[2][F_DIM];
  __shared__ float sB[2][F_DIM];
  __shared__ float red[4];
  const int tid = threadIdx.x;
  const int b = blockIdx.x;
  const int j = tid & (H_DIM - 1);
  const int h = tid >> 7;

  {
    float m = 0.f;
#pragma unroll
    for (int t = 0; t < S2N; ++t)
      m += Xself[(size_t)(b * S2N + t) * 256 + tid];
    sA[1][tid] = m / (float)S2N;
    sA[0][tid] = feat[(size_t)batch[b] * F_DIM + tid];
  }
  __syncthreads();

  const float* __restrict__ W0 = h ? Wn0 : Ws0;
  float a0 = 0.f;
#pragma unroll 4
  for (int k4 = 0; k4 < F_DIM / 4; ++k4) {
    float4 s4 = *reinterpret_cast<const float4*>(&sA[h][k4 * 4]);
    a0 += s4.x * W0[(k4 * 4 + 0) * H_DIM + j];
    a0 += s4.y * W0[(k4 * 4 + 1) * H_DIM + j];
    a0 += s4.z * W0[(k4 * 4 + 2) * H_DIM + j];
    a0 += s4.w * W0[(k4 * 4 + 3) * H_DIM + j];
  }
  a0 = fmaxf(a0, 0.f);

  sB[0][tid] = a0;
  {
    float m = 0.f;
#pragma unroll
    for (int t = 0; t < S2N; ++t)
      m += h1out[(size_t)(b * S2N + t) * 256 + tid];
    sB[1][tid] = m / (float)S2N;
  }
  __syncthreads();

  const float* __restrict__ W1 = h ? Wn1 : Ws1;
  float a1 = 0.f;
#pragma unroll 4
  for (int k4 = 0; k4 < F_DIM / 4; ++k4) {
    float4 s4 = *reinterpret_cast<const float4*>(&sB[h][k4 * 4]);
    a1 += s4.x * W1[(k4 * 4 + 0) * H_DIM + j];
    a1 += s4.y * W1[(k4 * 4 + 1) * H_DIM + j];
    a1 += s4.z * W1[(k4 * 4 + 2) * H_DIM + j];
    a1 += s4.w * W1[(k4 * 4 + 3) * H_DIM + j];
  }

  float s = a1 * a1;
#pragma unroll
  for (int off = 32; off > 0; off >>= 1) s += __shfl_xor(s, off);
  if ((tid & 63) == 0) red[tid >> 6] = s;
  __syncthreads();
  float tot = red[0] + red[1] + red[2] + red[3];
  float inv = 1.f / fmaxf(sqrtf(tot), 1e-12f);
  out[(size_t)b * 256 + tid] = a1 * inv;
}

// ---------------------------------------------------------------------------
extern "C" void kernel_launch(void* const* d_in, const int* in_sizes, int n_in,
                              void* d_out, int out_size, void* d_ws, size_t ws_size,
                              hipStream_t stream) {
  const float* feat  = (const float*)d_in[0];
  const int*   adj   = (const int*)d_in[1];
  const int*   batch = (const int*)d_in[2];
  const float* Ws0   = (const float*)d_in[3];
  const float* Wn0   = (const float*)d_in[4];
  const float* Ws1   = (const float*)d_in[5];
  const float* Wn1   = (const float*)d_in[6];
  float* out = (float*)d_out;

  char* ws = (char*)d_ws;
  float* Xself = (float*)(ws);                    // 5120*256*4 = 5.25 MB
  float* h1out = (float*)(ws + (8u << 20));       // 5120*256*4 = 5.25 MB

  k_gmm <<<NS1 / RMM, 512, 0, stream>>>(feat, adj, batch, Ws0, Wn0, Xself, h1out);
  k_tail<<<BATCH, 256, 0, stream>>>(feat, batch, Xself, h1out, Ws0, Wn0, Ws1, Wn1, out);
}